// Round 1
// baseline (390.999 us; speedup 1.0000x reference)
//
#include <hip/hip_runtime.h>
#include <hip/hip_bf16.h>
#include <math.h>

#define EPS 1e-5f

static constexpr int Bb = 8;
static constexpr int Ss = 8192;
static constexpr int Dd = 1024;   // QD = KD = AD

// ---------- helpers ----------

__device__ __forceinline__ float blk_reduce(float v, bool ismax, volatile float* lds) {
  // blockDim.x == 256 (4 waves of 64)
#pragma unroll
  for (int msk = 32; msk; msk >>= 1) {
    float o = __shfl_xor(v, msk);
    v = ismax ? fmaxf(v, o) : (v + o);
  }
  int w = threadIdx.x >> 6;
  __syncthreads();                       // protect lds reuse across calls
  if ((threadIdx.x & 63) == 0) lds[w] = v;
  __syncthreads();
  return ismax ? fmaxf(fmaxf(lds[0], lds[1]), fmaxf(lds[2], lds[3]))
               : (lds[0] + lds[1] + lds[2] + lds[3]);
}

__device__ __forceinline__ float quantf(float x, float c) {
  // round-half-to-even like jnp.round, clip to [-128,127]
  return fminf(fmaxf(rintf(x * c), -128.f), 127.f);
}

__device__ __forceinline__ float ternf(float w, float s) {
  // clip(round(w / s), -1, 1)   (true division to mirror reference)
  return fminf(fmaxf(rintf(w / s), -1.f), 1.f);
}

// ---------- K1/K2: weight abs-mean scales ----------

__global__ __launch_bounds__(256) void k_abs_partial(
    const float* __restrict__ w0, const float* __restrict__ w1,
    const float* __restrict__ w2, const float* __restrict__ w3,
    double* __restrict__ part)
{
  int seg = blockIdx.x >> 6;   // 0..3
  int blk = blockIdx.x & 63;
  const float* w = seg == 0 ? w0 : seg == 1 ? w1 : seg == 2 ? w2 : w3;
  int n4 = (seg == 3 ? (1024 * 2048) : (1024 * 1024)) >> 2;
  const float4* w4 = (const float4*)w;
  double acc = 0.0;
  for (int i = blk * 256 + threadIdx.x; i < n4; i += 64 * 256) {
    float4 v = w4[i];
    acc += (double)fabsf(v.x) + (double)fabsf(v.y)
         + (double)fabsf(v.z) + (double)fabsf(v.w);
  }
  __shared__ double sred[256];
  sred[threadIdx.x] = acc;
  __syncthreads();
  for (int s = 128; s > 0; s >>= 1) {
    if (threadIdx.x < s) sred[threadIdx.x] += sred[threadIdx.x + s];
    __syncthreads();
  }
  if (threadIdx.x == 0) part[blockIdx.x] = sred[0];
}

__global__ void k_abs_final(const double* __restrict__ part, float* __restrict__ scales)
{
  int seg = threadIdx.x;
  if (seg >= 4) return;
  double s = 0.0;
  for (int i = 0; i < 64; i++) s += part[seg * 64 + i];
  double n = (seg == 3) ? 2097152.0 : 1048576.0;
  scales[seg] = (float)(s / n) + EPS;
}

// ---------- K3: quantize query rows ----------

__global__ __launch_bounds__(256) void k_quant_query(
    const float* __restrict__ x, char* __restrict__ qout, float* __restrict__ gout)
{
  __shared__ float red[4];
  int b = blockIdx.x, tid = threadIdx.x;
  float4 v = ((const float4*)(x + (size_t)b * Dd))[tid];
  float am = fmaxf(fmaxf(fabsf(v.x), fabsf(v.y)), fmaxf(fabsf(v.z), fabsf(v.w)));
  am = blk_reduce(am, true, red);
  float g = am + EPS;
  float c = 127.0f / g;
  char4 q;
  q.x = (signed char)(int)quantf(v.x, c);
  q.y = (signed char)(int)quantf(v.y, c);
  q.z = (signed char)(int)quantf(v.z, c);
  q.w = (signed char)(int)quantf(v.w, c);
  ((char4*)qout)[b * 256 + tid] = q;
  if (tid == 0) gout[b] = g;
}

// ---------- ternary GEMV, int8 activations (wave per output) ----------

__global__ __launch_bounds__(256) void k_tern_gemv_i8(
    const char* __restrict__ qact, const float* __restrict__ gact,
    const float* __restrict__ W, const float* __restrict__ bias,
    const float* __restrict__ scales, int sidx,
    float* __restrict__ out, int K, int N)
{
  int wave = blockIdx.x * 4 + (threadIdx.x >> 6);
  int lane = threadIdx.x & 63;
  int b = wave / N, o = wave - b * N;
  float s = scales[sidx];
  const float4* wr = (const float4*)(W + (size_t)o * K);
  const char4*  qr = (const char4*)(qact + (size_t)b * K);
  int n4 = K >> 2;
  float acc = 0.f;
  for (int i = lane; i < n4; i += 64) {
    float4 w4 = wr[i];
    char4  q4 = qr[i];
    acc += (float)q4.x * ternf(w4.x, s);
    acc += (float)q4.y * ternf(w4.y, s);
    acc += (float)q4.z * ternf(w4.z, s);
    acc += (float)q4.w * ternf(w4.w, s);
  }
#pragma unroll
  for (int m = 32; m; m >>= 1) acc += __shfl_xor(acc, m);
  if (lane == 0) {
    float g = gact[b];
    out[(size_t)b * N + o] = s * (g / 127.0f) * acc + bias[o];
  }
}

// ---------- ternary GEMV, fp32 activations (wave per output) ----------

__global__ __launch_bounds__(256) void k_tern_gemv_f32(
    const float* __restrict__ act, const float* __restrict__ W,
    const float* __restrict__ bias, const float* __restrict__ scales, int sidx,
    float* __restrict__ out, int K, int N)
{
  int wave = blockIdx.x * 4 + (threadIdx.x >> 6);
  int lane = threadIdx.x & 63;
  int b = wave / N, o = wave - b * N;
  float s = scales[sidx];
  const float4* wr = (const float4*)(W + (size_t)o * K);
  const float4* ar = (const float4*)(act + (size_t)b * K);
  int n4 = K >> 2;
  float acc = 0.f;
  for (int i = lane; i < n4; i += 64) {
    float4 w4 = wr[i];
    float4 a4 = ar[i];
    acc += a4.x * ternf(w4.x, s);
    acc += a4.y * ternf(w4.y, s);
    acc += a4.z * ternf(w4.z, s);
    acc += a4.w * ternf(w4.w, s);
  }
#pragma unroll
  for (int m = 32; m; m >>= 1) acc += __shfl_xor(acc, m);
  if (lane == 0) out[(size_t)b * N + o] = s * acc + bias[o];
}

// ---------- K5: qk[b,d] = s_wk * sum_a q[b,a]*tern(Wk[a,d]); also q.b_k ----------

__global__ __launch_bounds__(256) void k_qk(
    const float* __restrict__ q, const float* __restrict__ Wk,
    const float* __restrict__ bk, const float* __restrict__ scales,
    float* __restrict__ qk, float* __restrict__ qdotbk)
{
  __shared__ float qrow[Dd];
  __shared__ float red[4];
  int b = blockIdx.x >> 2, ch = blockIdx.x & 3;
  int tid = threadIdx.x;
  for (int i = tid; i < Dd; i += 256) qrow[i] = q[(size_t)b * Dd + i];
  __syncthreads();
  float s = scales[1];
  int d = ch * 256 + tid;
  float acc = 0.f;
  for (int a = 0; a < Dd; a++) {
    float w = Wk[(size_t)a * Dd + d];
    acc += qrow[a] * ternf(w, s);
  }
  qk[(size_t)b * Dd + d] = s * acc;
  if (ch == 0) {
    float p = 0.f;
    for (int a = tid; a < Dd; a += 256) p += qrow[a] * bk[a];
    p = blk_reduce(p, false, red);
    if (tid == 0) qdotbk[b] = p;
  }
}

// ---------- K6: the fused streaming pass over context_memory ----------

__global__ __launch_bounds__(256) void k_pass(
    const float* __restrict__ X, const float* __restrict__ qk,
    const float* __restrict__ qdotbk,
    float* __restrict__ m_part, float* __restrict__ l_part,
    float* __restrict__ t_part, int NW)
{
  __shared__ float red[4];
  int b  = blockIdx.x / NW;
  int wg = blockIdx.x - b * NW;
  int tok = Ss / NW;
  int s0 = wg * tok;
  int tid = threadIdx.x;

  float4 qv = ((const float4*)(qk + (size_t)b * Dd))[tid];
  float qb = qdotbk[b];
  const float4* Xb = (const float4*)(X + ((size_t)b * Ss + s0) * Dd);

  float m = -INFINITY, l = 0.f;
  float t0 = 0.f, t1 = 0.f, t2 = 0.f, t3 = 0.f;

  float4 x = Xb[tid];
  for (int i = 0; i < tok; i++) {
    int nidx = (i + 1 < tok) ? (i + 1) : i;          // branch-free prefetch
    float4 xn = Xb[(size_t)nidx * 256 + tid];

    float am = fmaxf(fmaxf(fabsf(x.x), fabsf(x.y)), fmaxf(fabsf(x.z), fabsf(x.w)));
    am = blk_reduce(am, true, red);
    float g = am + EPS;
    float c = 127.0f / g;
    float q0 = quantf(x.x, c);
    float q1 = quantf(x.y, c);
    float q2 = quantf(x.z, c);
    float q3 = quantf(x.w, c);

    float dt = q0 * qv.x + q1 * qv.y + q2 * qv.z + q3 * qv.w;
    dt = blk_reduce(dt, false, red);

    float score = (dt * (g / 127.0f) + qb) * 0.03125f;   // / sqrt(1024)
    float mn = fmaxf(m, score);
    float scl = expf(m - mn);       // first iter: exp(-inf)=0
    float p   = expf(score - mn);
    l = l * scl + p;
    float coeff = p * (g / 127.0f);
    t0 = t0 * scl + coeff * q0;
    t1 = t1 * scl + coeff * q1;
    t2 = t2 * scl + coeff * q2;
    t3 = t3 * scl + coeff * q3;
    m = mn;
    x = xn;
  }

  size_t pidx = (size_t)b * NW + wg;
  ((float4*)t_part)[pidx * 256 + tid] = make_float4(t0, t1, t2, t3);
  if (tid == 0) { m_part[pidx] = m; l_part[pidx] = l; }
}

// ---------- K7: combine partials -> normalized t[b,d] ----------

__global__ __launch_bounds__(256) void k_combine(
    const float* __restrict__ m_part, const float* __restrict__ l_part,
    const float* __restrict__ t_part, float* __restrict__ t, int NW)
{
  __shared__ float wsh[256];
  __shared__ float red[4];
  int b = blockIdx.x, tid = threadIdx.x;
  float mi = (tid < NW) ? m_part[(size_t)b * NW + tid] : -INFINITY;
  float M = blk_reduce(mi, true, red);
  float wi = (tid < NW) ? expf(mi - M) : 0.f;
  float li = (tid < NW) ? l_part[(size_t)b * NW + tid] * wi : 0.f;
  float L = blk_reduce(li, false, red);
  wsh[tid] = wi;
  __syncthreads();
  float ax = 0.f, ay = 0.f, az = 0.f, aw = 0.f;
  for (int i = 0; i < NW; i++) {
    float w = wsh[i];
    float4 tp = ((const float4*)t_part)[((size_t)b * NW + i) * 256 + tid];
    ax += w * tp.x; ay += w * tp.y; az += w * tp.z; aw += w * tp.w;
  }
  float inv = 1.0f / L;
  ((float4*)t)[(size_t)b * 256 + tid] = make_float4(ax * inv, ay * inv, az * inv, aw * inv);
}

// ---------- K9: quantize combined = [query, ctx] ----------

__global__ __launch_bounds__(256) void k_quant_comb(
    const float* __restrict__ query, const float* __restrict__ ctx,
    char* __restrict__ qout, float* __restrict__ gout)
{
  __shared__ float red[4];
  int b = blockIdx.x, tid = threadIdx.x;
  float4 vq = ((const float4*)(query + (size_t)b * Dd))[tid];
  float4 vc = ((const float4*)(ctx   + (size_t)b * Dd))[tid];
  float am = fmaxf(
      fmaxf(fmaxf(fabsf(vq.x), fabsf(vq.y)), fmaxf(fabsf(vq.z), fabsf(vq.w))),
      fmaxf(fmaxf(fabsf(vc.x), fabsf(vc.y)), fmaxf(fabsf(vc.z), fabsf(vc.w))));
  am = blk_reduce(am, true, red);
  float g = am + EPS;
  float c = 127.0f / g;
  char4 a, d;
  a.x = (signed char)(int)quantf(vq.x, c);
  a.y = (signed char)(int)quantf(vq.y, c);
  a.z = (signed char)(int)quantf(vq.z, c);
  a.w = (signed char)(int)quantf(vq.w, c);
  d.x = (signed char)(int)quantf(vc.x, c);
  d.y = (signed char)(int)quantf(vc.y, c);
  d.z = (signed char)(int)quantf(vc.z, c);
  d.w = (signed char)(int)quantf(vc.w, c);
  ((char4*)qout)[b * 512 + tid] = a;
  ((char4*)qout)[b * 512 + 256 + tid] = d;
  if (tid == 0) gout[b] = g;
}

// ---------- launch ----------

extern "C" void kernel_launch(void* const* d_in, const int* in_sizes, int n_in,
                              void* d_out, int out_size, void* d_ws, size_t ws_size,
                              hipStream_t stream)
{
  const float* query = (const float*)d_in[0];
  const float* X     = (const float*)d_in[1];
  const float* w_q   = (const float*)d_in[2];
  const float* b_q   = (const float*)d_in[3];
  const float* w_k   = (const float*)d_in[4];
  const float* b_k   = (const float*)d_in[5];
  const float* w_v   = (const float*)d_in[6];
  const float* b_v   = (const float*)d_in[7];
  const float* w_c   = (const float*)d_in[8];
  const float* b_c   = (const float*)d_in[9];
  float* out = (float*)d_out;
  char* ws = (char*)d_ws;

  size_t off = 0;
  auto alloc = [&](size_t bytes) -> size_t {
    size_t o = off;
    off += (bytes + 255) & ~(size_t)255;
    return o;
  };
  size_t o_part   = alloc(256 * sizeof(double));
  size_t o_scales = alloc(4 * sizeof(float));
  size_t o_gq     = alloc(Bb * sizeof(float));
  size_t o_qq     = alloc((size_t)Bb * Dd);          // int8 query
  size_t o_q      = alloc((size_t)Bb * Dd * 4);
  size_t o_qk     = alloc((size_t)Bb * Dd * 4);
  size_t o_qbk    = alloc(Bb * sizeof(float));
  size_t o_t      = alloc((size_t)Bb * Dd * 4);
  size_t o_ctx    = alloc((size_t)Bb * Dd * 4);
  size_t o_gc     = alloc(Bb * sizeof(float));
  size_t o_qc     = alloc((size_t)Bb * 2 * Dd);      // int8 combined
  size_t base_end = off;

  int NW = 256;
  for (;;) {
    size_t need = base_end
      + ((((size_t)Bb * NW * 4) + 255) & ~(size_t)255) * 2
      + ((((size_t)Bb * NW * Dd * 4) + 255) & ~(size_t)255);
    if (need <= ws_size || NW == 32) break;
    NW >>= 1;
  }
  size_t o_mp = alloc((size_t)Bb * NW * 4);
  size_t o_lp = alloc((size_t)Bb * NW * 4);
  size_t o_tp = alloc((size_t)Bb * NW * Dd * 4);

  double* part   = (double*)(ws + o_part);
  float*  scales = (float*)(ws + o_scales);
  float*  gq     = (float*)(ws + o_gq);
  char*   qq     = (char*)(ws + o_qq);
  float*  qv     = (float*)(ws + o_q);
  float*  qk     = (float*)(ws + o_qk);
  float*  qbk    = (float*)(ws + o_qbk);
  float*  tvec   = (float*)(ws + o_t);
  float*  ctx    = (float*)(ws + o_ctx);
  float*  gc     = (float*)(ws + o_gc);
  char*   qc     = (char*)(ws + o_qc);
  float*  mp     = (float*)(ws + o_mp);
  float*  lp     = (float*)(ws + o_lp);
  float*  tp     = (float*)(ws + o_tp);

  k_abs_partial<<<256, 256, 0, stream>>>(w_q, w_k, w_v, w_c, part);
  k_abs_final<<<1, 64, 0, stream>>>(part, scales);
  k_quant_query<<<Bb, 256, 0, stream>>>(query, qq, gq);
  k_tern_gemv_i8<<<(Bb * Dd) / 4, 256, 0, stream>>>(qq, gq, w_q, b_q, scales, 0, qv, Dd, Dd);
  k_qk<<<Bb * 4, 256, 0, stream>>>(qv, w_k, b_k, scales, qk, qbk);
  k_pass<<<Bb * NW, 256, 0, stream>>>(X, qk, qbk, mp, lp, tp, NW);
  k_combine<<<Bb, 256, 0, stream>>>(mp, lp, tp, tvec, NW);
  k_tern_gemv_f32<<<(Bb * Dd) / 4, 256, 0, stream>>>(tvec, w_v, b_v, scales, 2, ctx, Dd, Dd);
  k_quant_comb<<<Bb, 256, 0, stream>>>(query, ctx, qc, gc);
  k_tern_gemv_i8<<<(Bb * Dd) / 4, 256, 0, stream>>>(qc, gc, w_c, b_c, scales, 3, out, 2 * Dd, Dd);
}

// Round 2
// 159.930 us; speedup vs baseline: 2.4448x; 2.4448x over previous
//
#include <hip/hip_runtime.h>
#include <hip/hip_bf16.h>
#include <math.h>

#define EPS 1e-5f

static constexpr int Bb = 8;
static constexpr int Ss = 8192;
static constexpr int Dd = 1024;   // QD = KD = AD

// ---------- helpers ----------

__device__ __forceinline__ float blk_reduce(float v, bool ismax, volatile float* lds) {
  // blockDim.x == 256 (4 waves of 64)
#pragma unroll
  for (int msk = 32; msk; msk >>= 1) {
    float o = __shfl_xor(v, msk);
    v = ismax ? fmaxf(v, o) : (v + o);
  }
  int w = threadIdx.x >> 6;
  __syncthreads();                       // protect lds reuse across calls
  if ((threadIdx.x & 63) == 0) lds[w] = v;
  __syncthreads();
  return ismax ? fmaxf(fmaxf(lds[0], lds[1]), fmaxf(lds[2], lds[3]))
               : (lds[0] + lds[1] + lds[2] + lds[3]);
}

__device__ __forceinline__ float quantf(float x, float c) {
  // round-half-to-even like jnp.round, clip to [-128,127]
  return fminf(fmaxf(rintf(x * c), -128.f), 127.f);
}

__device__ __forceinline__ float ternf(float w, float s) {
  // clip(round(w / s), -1, 1)   (true division to mirror reference)
  return fminf(fmaxf(rintf(w / s), -1.f), 1.f);
}

// ---------- K1/K2: weight abs-mean scales ----------

__global__ __launch_bounds__(256) void k_abs_partial(
    const float* __restrict__ w0, const float* __restrict__ w1,
    const float* __restrict__ w2, const float* __restrict__ w3,
    double* __restrict__ part)
{
  int seg = blockIdx.x >> 6;   // 0..3
  int blk = blockIdx.x & 63;
  const float* w = seg == 0 ? w0 : seg == 1 ? w1 : seg == 2 ? w2 : w3;
  int n4 = (seg == 3 ? (1024 * 2048) : (1024 * 1024)) >> 2;
  const float4* w4 = (const float4*)w;
  double acc = 0.0;
  for (int i = blk * 256 + threadIdx.x; i < n4; i += 64 * 256) {
    float4 v = w4[i];
    acc += (double)fabsf(v.x) + (double)fabsf(v.y)
         + (double)fabsf(v.z) + (double)fabsf(v.w);
  }
  __shared__ double sred[256];
  sred[threadIdx.x] = acc;
  __syncthreads();
  for (int s = 128; s > 0; s >>= 1) {
    if (threadIdx.x < s) sred[threadIdx.x] += sred[threadIdx.x + s];
    __syncthreads();
  }
  if (threadIdx.x == 0) part[blockIdx.x] = sred[0];
}

__global__ void k_abs_final(const double* __restrict__ part, float* __restrict__ scales)
{
  int seg = threadIdx.x;
  if (seg >= 4) return;
  double s = 0.0;
  for (int i = 0; i < 64; i++) s += part[seg * 64 + i];
  double n = (seg == 3) ? 2097152.0 : 1048576.0;
  scales[seg] = (float)(s / n) + EPS;
}

// ---------- K3: quantize query rows ----------

__global__ __launch_bounds__(256) void k_quant_query(
    const float* __restrict__ x, char* __restrict__ qout, float* __restrict__ gout)
{
  __shared__ float red[4];
  int b = blockIdx.x, tid = threadIdx.x;
  float4 v = ((const float4*)(x + (size_t)b * Dd))[tid];
  float am = fmaxf(fmaxf(fabsf(v.x), fabsf(v.y)), fmaxf(fabsf(v.z), fabsf(v.w)));
  am = blk_reduce(am, true, red);
  float g = am + EPS;
  float c = 127.0f / g;
  char4 q;
  q.x = (signed char)(int)quantf(v.x, c);
  q.y = (signed char)(int)quantf(v.y, c);
  q.z = (signed char)(int)quantf(v.z, c);
  q.w = (signed char)(int)quantf(v.w, c);
  ((char4*)qout)[b * 256 + tid] = q;
  if (tid == 0) gout[b] = g;
}

// ---------- ternary GEMV, int8 activations (wave per output) ----------

__global__ __launch_bounds__(256) void k_tern_gemv_i8(
    const char* __restrict__ qact, const float* __restrict__ gact,
    const float* __restrict__ W, const float* __restrict__ bias,
    const float* __restrict__ scales, int sidx,
    float* __restrict__ out, int K, int N)
{
  int wave = blockIdx.x * 4 + (threadIdx.x >> 6);
  int lane = threadIdx.x & 63;
  int b = wave / N, o = wave - b * N;
  float s = scales[sidx];
  const float4* wr = (const float4*)(W + (size_t)o * K);
  const char4*  qr = (const char4*)(qact + (size_t)b * K);
  int n4 = K >> 2;
  float acc = 0.f;
  for (int i = lane; i < n4; i += 64) {
    float4 w4 = wr[i];
    char4  q4 = qr[i];
    acc += (float)q4.x * ternf(w4.x, s);
    acc += (float)q4.y * ternf(w4.y, s);
    acc += (float)q4.z * ternf(w4.z, s);
    acc += (float)q4.w * ternf(w4.w, s);
  }
#pragma unroll
  for (int m = 32; m; m >>= 1) acc += __shfl_xor(acc, m);
  if (lane == 0) {
    float g = gact[b];
    out[(size_t)b * N + o] = s * (g / 127.0f) * acc + bias[o];
  }
}

// ---------- ternary GEMV, fp32 activations (wave per output) ----------

__global__ __launch_bounds__(256) void k_tern_gemv_f32(
    const float* __restrict__ act, const float* __restrict__ W,
    const float* __restrict__ bias, const float* __restrict__ scales, int sidx,
    float* __restrict__ out, int K, int N)
{
  int wave = blockIdx.x * 4 + (threadIdx.x >> 6);
  int lane = threadIdx.x & 63;
  int b = wave / N, o = wave - b * N;
  float s = scales[sidx];
  const float4* wr = (const float4*)(W + (size_t)o * K);
  const float4* ar = (const float4*)(act + (size_t)b * K);
  int n4 = K >> 2;
  float acc = 0.f;
  for (int i = lane; i < n4; i += 64) {
    float4 w4 = wr[i];
    float4 a4 = ar[i];
    acc += a4.x * ternf(w4.x, s);
    acc += a4.y * ternf(w4.y, s);
    acc += a4.z * ternf(w4.z, s);
    acc += a4.w * ternf(w4.w, s);
  }
#pragma unroll
  for (int m = 32; m; m >>= 1) acc += __shfl_xor(acc, m);
  if (lane == 0) out[(size_t)b * N + o] = s * acc + bias[o];
}

// ---------- K5a: qk partials over a-chunks ----------
// part[ch][b][d] = sum_{a in chunk ch} q[b][a] * tern(Wk[a][d])
// grid = NCH blocks, 256 threads, each thread owns 4 consecutive d-columns.
// Each 16B weight load is reused by all 8 batch rows (32 FMA / load).

__global__ __launch_bounds__(256) void k_qk_part(
    const float* __restrict__ q, const float* __restrict__ Wk,
    const float* __restrict__ scales, float* __restrict__ part, int RC)
{
  __shared__ float qs[1024];           // [b][a] chunk, stride RC (RC <= 128)
  int ch = blockIdx.x;
  int a0 = ch * RC;
  int tid = threadIdx.x;
  for (int i = tid; i < 8 * RC; i += 256) {
    int b = i / RC, a = i - b * RC;
    qs[i] = q[(size_t)b * Dd + a0 + a];
  }
  __syncthreads();
  float s = scales[1];
  float4 acc[8];
#pragma unroll
  for (int b = 0; b < 8; b++) acc[b] = make_float4(0.f, 0.f, 0.f, 0.f);
  const float4* Wr = (const float4*)(Wk + (size_t)a0 * Dd);
  for (int i = 0; i < RC; i++) {
    float4 w = Wr[(size_t)i * 256 + tid];
    float4 t;
    t.x = ternf(w.x, s); t.y = ternf(w.y, s);
    t.z = ternf(w.z, s); t.w = ternf(w.w, s);
#pragma unroll
    for (int b = 0; b < 8; b++) {
      float qb = qs[b * RC + i];
      acc[b].x += qb * t.x; acc[b].y += qb * t.y;
      acc[b].z += qb * t.z; acc[b].w += qb * t.w;
    }
  }
#pragma unroll
  for (int b = 0; b < 8; b++)
    ((float4*)part)[((size_t)ch * 8 + b) * 256 + tid] = acc[b];
}

// ---------- K5b: combine qk partials; also q . b_k ----------

__global__ __launch_bounds__(256) void k_qk_comb(
    const float* __restrict__ part, const float* __restrict__ q,
    const float* __restrict__ bk, const float* __restrict__ scales,
    float* __restrict__ qk, float* __restrict__ qdotbk, int NCH)
{
  __shared__ float red[4];
  int b = blockIdx.x, tid = threadIdx.x;
  float s = scales[1];
  float4 acc = make_float4(0.f, 0.f, 0.f, 0.f);
  for (int ch = 0; ch < NCH; ch++) {
    float4 p = ((const float4*)part)[((size_t)ch * 8 + b) * 256 + tid];
    acc.x += p.x; acc.y += p.y; acc.z += p.z; acc.w += p.w;
  }
  ((float4*)qk)[(size_t)b * 256 + tid] =
      make_float4(s * acc.x, s * acc.y, s * acc.z, s * acc.w);
  float p = 0.f;
  for (int a = tid; a < Dd; a += 256) p += q[(size_t)b * Dd + a] * bk[a];
  p = blk_reduce(p, false, red);
  if (tid == 0) qdotbk[b] = p;
}

// ---------- K6: the fused streaming pass over context_memory ----------

__global__ __launch_bounds__(256) void k_pass(
    const float* __restrict__ X, const float* __restrict__ qk,
    const float* __restrict__ qdotbk,
    float* __restrict__ m_part, float* __restrict__ l_part,
    float* __restrict__ t_part, int NW)
{
  __shared__ float red[4];
  int b  = blockIdx.x / NW;
  int wg = blockIdx.x - b * NW;
  int tok = Ss / NW;
  int s0 = wg * tok;
  int tid = threadIdx.x;

  float4 qv = ((const float4*)(qk + (size_t)b * Dd))[tid];
  float qb = qdotbk[b];
  const float4* Xb = (const float4*)(X + ((size_t)b * Ss + s0) * Dd);

  float m = -INFINITY, l = 0.f;
  float t0 = 0.f, t1 = 0.f, t2 = 0.f, t3 = 0.f;

  float4 x = Xb[tid];
  for (int i = 0; i < tok; i++) {
    int nidx = (i + 1 < tok) ? (i + 1) : i;          // branch-free prefetch
    float4 xn = Xb[(size_t)nidx * 256 + tid];

    float am = fmaxf(fmaxf(fabsf(x.x), fabsf(x.y)), fmaxf(fabsf(x.z), fabsf(x.w)));
    am = blk_reduce(am, true, red);
    float g = am + EPS;
    float c = 127.0f / g;
    float q0 = quantf(x.x, c);
    float q1 = quantf(x.y, c);
    float q2 = quantf(x.z, c);
    float q3 = quantf(x.w, c);

    float dt = q0 * qv.x + q1 * qv.y + q2 * qv.z + q3 * qv.w;
    dt = blk_reduce(dt, false, red);

    float score = (dt * (g / 127.0f) + qb) * 0.03125f;   // / sqrt(1024)
    float mn = fmaxf(m, score);
    float scl = expf(m - mn);       // first iter: exp(-inf)=0
    float p   = expf(score - mn);
    l = l * scl + p;
    float coeff = p * (g / 127.0f);
    t0 = t0 * scl + coeff * q0;
    t1 = t1 * scl + coeff * q1;
    t2 = t2 * scl + coeff * q2;
    t3 = t3 * scl + coeff * q3;
    m = mn;
    x = xn;
  }

  size_t pidx = (size_t)b * NW + wg;
  ((float4*)t_part)[pidx * 256 + tid] = make_float4(t0, t1, t2, t3);
  if (tid == 0) { m_part[pidx] = m; l_part[pidx] = l; }
}

// ---------- K7: combine partials -> normalized t[b,d] ----------

__global__ __launch_bounds__(256) void k_combine(
    const float* __restrict__ m_part, const float* __restrict__ l_part,
    const float* __restrict__ t_part, float* __restrict__ t, int NW)
{
  __shared__ float wsh[256];
  __shared__ float red[4];
  int b = blockIdx.x, tid = threadIdx.x;
  float mi = (tid < NW) ? m_part[(size_t)b * NW + tid] : -INFINITY;
  float M = blk_reduce(mi, true, red);
  float wi = (tid < NW) ? expf(mi - M) : 0.f;
  float li = (tid < NW) ? l_part[(size_t)b * NW + tid] * wi : 0.f;
  float L = blk_reduce(li, false, red);
  wsh[tid] = wi;
  __syncthreads();
  float ax = 0.f, ay = 0.f, az = 0.f, aw = 0.f;
  for (int i = 0; i < NW; i++) {
    float w = wsh[i];
    float4 tp = ((const float4*)t_part)[((size_t)b * NW + i) * 256 + tid];
    ax += w * tp.x; ay += w * tp.y; az += w * tp.z; aw += w * tp.w;
  }
  float inv = 1.0f / L;
  ((float4*)t)[(size_t)b * 256 + tid] = make_float4(ax * inv, ay * inv, az * inv, aw * inv);
}

// ---------- K9: quantize combined = [query, ctx] ----------

__global__ __launch_bounds__(256) void k_quant_comb(
    const float* __restrict__ query, const float* __restrict__ ctx,
    char* __restrict__ qout, float* __restrict__ gout)
{
  __shared__ float red[4];
  int b = blockIdx.x, tid = threadIdx.x;
  float4 vq = ((const float4*)(query + (size_t)b * Dd))[tid];
  float4 vc = ((const float4*)(ctx   + (size_t)b * Dd))[tid];
  float am = fmaxf(
      fmaxf(fmaxf(fabsf(vq.x), fabsf(vq.y)), fmaxf(fabsf(vq.z), fabsf(vq.w))),
      fmaxf(fmaxf(fabsf(vc.x), fabsf(vc.y)), fmaxf(fabsf(vc.z), fabsf(vc.w))));
  am = blk_reduce(am, true, red);
  float g = am + EPS;
  float c = 127.0f / g;
  char4 a, d;
  a.x = (signed char)(int)quantf(vq.x, c);
  a.y = (signed char)(int)quantf(vq.y, c);
  a.z = (signed char)(int)quantf(vq.z, c);
  a.w = (signed char)(int)quantf(vq.w, c);
  d.x = (signed char)(int)quantf(vc.x, c);
  d.y = (signed char)(int)quantf(vc.y, c);
  d.z = (signed char)(int)quantf(vc.z, c);
  d.w = (signed char)(int)quantf(vc.w, c);
  ((char4*)qout)[b * 512 + tid] = a;
  ((char4*)qout)[b * 512 + 256 + tid] = d;
  if (tid == 0) gout[b] = g;
}

// ---------- launch ----------

extern "C" void kernel_launch(void* const* d_in, const int* in_sizes, int n_in,
                              void* d_out, int out_size, void* d_ws, size_t ws_size,
                              hipStream_t stream)
{
  const float* query = (const float*)d_in[0];
  const float* X     = (const float*)d_in[1];
  const float* w_q   = (const float*)d_in[2];
  const float* b_q   = (const float*)d_in[3];
  const float* w_k   = (const float*)d_in[4];
  const float* b_k   = (const float*)d_in[5];
  const float* w_v   = (const float*)d_in[6];
  const float* b_v   = (const float*)d_in[7];
  const float* w_c   = (const float*)d_in[8];
  const float* b_c   = (const float*)d_in[9];
  float* out = (float*)d_out;
  char* ws = (char*)d_ws;

  size_t off = 0;
  auto alloc = [&](size_t bytes) -> size_t {
    size_t o = off;
    off += (bytes + 255) & ~(size_t)255;
    return o;
  };
  auto align256 = [](size_t bytes) -> size_t {
    return (bytes + 255) & ~(size_t)255;
  };
  size_t o_part   = alloc(256 * sizeof(double));
  size_t o_scales = alloc(4 * sizeof(float));
  size_t o_gq     = alloc(Bb * sizeof(float));
  size_t o_qq     = alloc((size_t)Bb * Dd);          // int8 query
  size_t o_q      = alloc((size_t)Bb * Dd * 4);
  size_t o_qk     = alloc((size_t)Bb * Dd * 4);
  size_t o_qbk    = alloc(Bb * sizeof(float));
  size_t o_t      = alloc((size_t)Bb * Dd * 4);
  size_t o_ctx    = alloc((size_t)Bb * Dd * 4);
  size_t o_gc     = alloc(Bb * sizeof(float));
  size_t o_qc     = alloc((size_t)Bb * 2 * Dd);      // int8 combined
  size_t base_end = off;

  // qk-partial chunk count, adaptive to ws_size (reserve NW=32 minimum for pass)
  int NCH = 64;
  for (;;) {
    size_t need = base_end
      + align256((size_t)NCH * 8 * Dd * 4)
      + align256((size_t)Bb * 32 * 4) * 2
      + align256((size_t)Bb * 32 * Dd * 4);
    if (need <= ws_size || NCH == 8) break;
    NCH >>= 1;
  }
  int RC = Dd / NCH;
  size_t o_qkp = alloc((size_t)NCH * 8 * Dd * 4);
  size_t qkp_end = off;

  int NW = 256;
  for (;;) {
    size_t need = qkp_end
      + align256((size_t)Bb * NW * 4) * 2
      + align256((size_t)Bb * NW * Dd * 4);
    if (need <= ws_size || NW == 32) break;
    NW >>= 1;
  }
  size_t o_mp = alloc((size_t)Bb * NW * 4);
  size_t o_lp = alloc((size_t)Bb * NW * 4);
  size_t o_tp = alloc((size_t)Bb * NW * Dd * 4);

  double* part   = (double*)(ws + o_part);
  float*  scales = (float*)(ws + o_scales);
  float*  gq     = (float*)(ws + o_gq);
  char*   qq     = (char*)(ws + o_qq);
  float*  qv     = (float*)(ws + o_q);
  float*  qk     = (float*)(ws + o_qk);
  float*  qbk    = (float*)(ws + o_qbk);
  float*  tvec   = (float*)(ws + o_t);
  float*  ctx    = (float*)(ws + o_ctx);
  float*  gc     = (float*)(ws + o_gc);
  char*   qc     = (char*)(ws + o_qc);
  float*  qkp    = (float*)(ws + o_qkp);
  float*  mp     = (float*)(ws + o_mp);
  float*  lp     = (float*)(ws + o_lp);
  float*  tp     = (float*)(ws + o_tp);

  k_abs_partial<<<256, 256, 0, stream>>>(w_q, w_k, w_v, w_c, part);
  k_abs_final<<<1, 64, 0, stream>>>(part, scales);
  k_quant_query<<<Bb, 256, 0, stream>>>(query, qq, gq);
  k_tern_gemv_i8<<<(Bb * Dd) / 4, 256, 0, stream>>>(qq, gq, w_q, b_q, scales, 0, qv, Dd, Dd);
  k_qk_part<<<NCH, 256, 0, stream>>>(qv, w_k, scales, qkp, RC);
  k_qk_comb<<<Bb, 256, 0, stream>>>(qkp, qv, b_k, scales, qk, qbk, NCH);
  k_pass<<<Bb * NW, 256, 0, stream>>>(X, qk, qbk, mp, lp, tp, NW);
  k_combine<<<Bb, 256, 0, stream>>>(mp, lp, tp, tvec, NW);
  k_tern_gemv_f32<<<(Bb * Dd) / 4, 256, 0, stream>>>(tvec, w_v, b_v, scales, 2, ctx, Dd, Dd);
  k_quant_comb<<<Bb, 256, 0, stream>>>(query, ctx, qc, gc);
  k_tern_gemv_i8<<<(Bb * Dd) / 4, 256, 0, stream>>>(qc, gc, w_c, b_c, scales, 3, out, 2 * Dd, Dd);
}

// Round 3
// 144.081 us; speedup vs baseline: 2.7137x; 1.1100x over previous
//
#include <hip/hip_runtime.h>
#include <hip/hip_bf16.h>
#include <math.h>

#define EPS 1e-5f

static constexpr int Bb = 8;
static constexpr int Ss = 8192;
static constexpr int Dd = 1024;   // QD = KD = AD

// ---------- helpers ----------

__device__ __forceinline__ float blk_reduce(float v, bool ismax, volatile float* lds) {
#pragma unroll
  for (int msk = 32; msk; msk >>= 1) {
    float o = __shfl_xor(v, msk);
    v = ismax ? fmaxf(v, o) : (v + o);
  }
  int w = threadIdx.x >> 6;
  __syncthreads();
  if ((threadIdx.x & 63) == 0) lds[w] = v;
  __syncthreads();
  return ismax ? fmaxf(fmaxf(lds[0], lds[1]), fmaxf(lds[2], lds[3]))
               : (lds[0] + lds[1] + lds[2] + lds[3]);
}

__device__ __forceinline__ float wred_max(float v) {
#pragma unroll
  for (int msk = 32; msk; msk >>= 1) v = fmaxf(v, __shfl_xor(v, msk));
  return v;
}

__device__ __forceinline__ float wred_sum(float v) {
#pragma unroll
  for (int msk = 32; msk; msk >>= 1) v += __shfl_xor(v, msk);
  return v;
}

__device__ __forceinline__ float quantf(float x, float c) {
  return fminf(fmaxf(rintf(x * c), -128.f), 127.f);
}

__device__ __forceinline__ float ternf(float w, float s) {
  return fminf(fmaxf(rintf(w / s), -1.f), 1.f);
}

// ---------- K1/K2: weight abs-mean scales ----------

__global__ __launch_bounds__(256) void k_abs_partial(
    const float* __restrict__ w0, const float* __restrict__ w1,
    const float* __restrict__ w2, const float* __restrict__ w3,
    double* __restrict__ part)
{
  int seg = blockIdx.x >> 6;
  int blk = blockIdx.x & 63;
  const float* w = seg == 0 ? w0 : seg == 1 ? w1 : seg == 2 ? w2 : w3;
  int n4 = (seg == 3 ? (1024 * 2048) : (1024 * 1024)) >> 2;
  const float4* w4 = (const float4*)w;
  double acc = 0.0;
  for (int i = blk * 256 + threadIdx.x; i < n4; i += 64 * 256) {
    float4 v = w4[i];
    acc += (double)fabsf(v.x) + (double)fabsf(v.y)
         + (double)fabsf(v.z) + (double)fabsf(v.w);
  }
  __shared__ double sred[256];
  sred[threadIdx.x] = acc;
  __syncthreads();
  for (int s = 128; s > 0; s >>= 1) {
    if (threadIdx.x < s) sred[threadIdx.x] += sred[threadIdx.x + s];
    __syncthreads();
  }
  if (threadIdx.x == 0) part[blockIdx.x] = sred[0];
}

__global__ void k_abs_final(const double* __restrict__ part, float* __restrict__ scales)
{
  int seg = threadIdx.x;
  if (seg >= 4) return;
  double s = 0.0;
  for (int i = 0; i < 64; i++) s += part[seg * 64 + i];
  double n = (seg == 3) ? 2097152.0 : 1048576.0;
  scales[seg] = (float)(s / n) + EPS;
}

// ---------- K3: quantize query rows ----------

__global__ __launch_bounds__(256) void k_quant_query(
    const float* __restrict__ x, char* __restrict__ qout, float* __restrict__ gout)
{
  __shared__ float red[4];
  int b = blockIdx.x, tid = threadIdx.x;
  float4 v = ((const float4*)(x + (size_t)b * Dd))[tid];
  float am = fmaxf(fmaxf(fabsf(v.x), fabsf(v.y)), fmaxf(fabsf(v.z), fabsf(v.w)));
  am = blk_reduce(am, true, red);
  float g = am + EPS;
  float c = 127.0f / g;
  char4 q;
  q.x = (signed char)(int)quantf(v.x, c);
  q.y = (signed char)(int)quantf(v.y, c);
  q.z = (signed char)(int)quantf(v.z, c);
  q.w = (signed char)(int)quantf(v.w, c);
  ((char4*)qout)[b * 256 + tid] = q;
  if (tid == 0) gout[b] = g;
}

// ---------- ternary GEMV, int8 activations ----------

__global__ __launch_bounds__(256) void k_tern_gemv_i8(
    const char* __restrict__ qact, const float* __restrict__ gact,
    const float* __restrict__ W, const float* __restrict__ bias,
    const float* __restrict__ scales, int sidx,
    float* __restrict__ out, int K, int N)
{
  int wave = blockIdx.x * 4 + (threadIdx.x >> 6);
  int lane = threadIdx.x & 63;
  int b = wave / N, o = wave - b * N;
  float s = scales[sidx];
  const float4* wr = (const float4*)(W + (size_t)o * K);
  const char4*  qr = (const char4*)(qact + (size_t)b * K);
  int n4 = K >> 2;
  float acc = 0.f;
  for (int i = lane; i < n4; i += 64) {
    float4 w4 = wr[i];
    char4  q4 = qr[i];
    acc += (float)q4.x * ternf(w4.x, s);
    acc += (float)q4.y * ternf(w4.y, s);
    acc += (float)q4.z * ternf(w4.z, s);
    acc += (float)q4.w * ternf(w4.w, s);
  }
#pragma unroll
  for (int m = 32; m; m >>= 1) acc += __shfl_xor(acc, m);
  if (lane == 0) {
    float g = gact[b];
    out[(size_t)b * N + o] = s * (g / 127.0f) * acc + bias[o];
  }
}

// ---------- ternary GEMV, fp32 activations ----------

__global__ __launch_bounds__(256) void k_tern_gemv_f32(
    const float* __restrict__ act, const float* __restrict__ W,
    const float* __restrict__ bias, const float* __restrict__ scales, int sidx,
    float* __restrict__ out, int K, int N)
{
  int wave = blockIdx.x * 4 + (threadIdx.x >> 6);
  int lane = threadIdx.x & 63;
  int b = wave / N, o = wave - b * N;
  float s = scales[sidx];
  const float4* wr = (const float4*)(W + (size_t)o * K);
  const float4* ar = (const float4*)(act + (size_t)b * K);
  int n4 = K >> 2;
  float acc = 0.f;
  for (int i = lane; i < n4; i += 64) {
    float4 w4 = wr[i];
    float4 a4 = ar[i];
    acc += a4.x * ternf(w4.x, s);
    acc += a4.y * ternf(w4.y, s);
    acc += a4.z * ternf(w4.z, s);
    acc += a4.w * ternf(w4.w, s);
  }
#pragma unroll
  for (int m = 32; m; m >>= 1) acc += __shfl_xor(acc, m);
  if (lane == 0) out[(size_t)b * N + o] = s * acc + bias[o];
}

// ---------- K5a: qk partials over a-chunks ----------

__global__ __launch_bounds__(256) void k_qk_part(
    const float* __restrict__ q, const float* __restrict__ Wk,
    const float* __restrict__ scales, float* __restrict__ part, int RC)
{
  __shared__ float qs[1024];
  int ch = blockIdx.x;
  int a0 = ch * RC;
  int tid = threadIdx.x;
  for (int i = tid; i < 8 * RC; i += 256) {
    int b = i / RC, a = i - b * RC;
    qs[i] = q[(size_t)b * Dd + a0 + a];
  }
  __syncthreads();
  float s = scales[1];
  float4 acc[8];
#pragma unroll
  for (int b = 0; b < 8; b++) acc[b] = make_float4(0.f, 0.f, 0.f, 0.f);
  const float4* Wr = (const float4*)(Wk + (size_t)a0 * Dd);
  for (int i = 0; i < RC; i++) {
    float4 w = Wr[(size_t)i * 256 + tid];
    float4 t;
    t.x = ternf(w.x, s); t.y = ternf(w.y, s);
    t.z = ternf(w.z, s); t.w = ternf(w.w, s);
#pragma unroll
    for (int b = 0; b < 8; b++) {
      float qb = qs[b * RC + i];
      acc[b].x += qb * t.x; acc[b].y += qb * t.y;
      acc[b].z += qb * t.z; acc[b].w += qb * t.w;
    }
  }
#pragma unroll
  for (int b = 0; b < 8; b++)
    ((float4*)part)[((size_t)ch * 8 + b) * 256 + tid] = acc[b];
}

// ---------- K5b: combine qk partials; also q . b_k ----------

__global__ __launch_bounds__(256) void k_qk_comb(
    const float* __restrict__ part, const float* __restrict__ q,
    const float* __restrict__ bk, const float* __restrict__ scales,
    float* __restrict__ qk, float* __restrict__ qdotbk, int NCH)
{
  __shared__ float red[4];
  int b = blockIdx.x, tid = threadIdx.x;
  float s = scales[1];
  float4 acc = make_float4(0.f, 0.f, 0.f, 0.f);
  for (int ch = 0; ch < NCH; ch++) {
    float4 p = ((const float4*)part)[((size_t)ch * 8 + b) * 256 + tid];
    acc.x += p.x; acc.y += p.y; acc.z += p.z; acc.w += p.w;
  }
  ((float4*)qk)[(size_t)b * 256 + tid] =
      make_float4(s * acc.x, s * acc.y, s * acc.z, s * acc.w);
  float p = 0.f;
  for (int a = tid; a < Dd; a += 256) p += q[(size_t)b * Dd + a] * bk[a];
  p = blk_reduce(p, false, red);
  if (tid == 0) qdotbk[b] = p;
}

// ---------- K6: fused streaming pass, one WAVE per token (no barriers) ----------
// Each wave of 64 lanes holds a full 1024-dim row (16 floats/lane).

__global__ __launch_bounds__(256) void k_pass(
    const float* __restrict__ X, const float* __restrict__ qk,
    const float* __restrict__ qdotbk,
    float* __restrict__ m_part, float* __restrict__ l_part,
    float* __restrict__ t_part, int NW)
{
  int b    = blockIdx.x / NW;
  int wg   = blockIdx.x - b * NW;
  int wv   = threadIdx.x >> 6;
  int lane = threadIdx.x & 63;
  int NWv  = NW * 4;
  int widx = wg * 4 + wv;
  int tok  = Ss / NWv;
  int s0   = widx * tok;

  const float4* qkb = (const float4*)(qk + (size_t)b * Dd);
  float4 qv0 = qkb[lane], qv1 = qkb[64 + lane], qv2 = qkb[128 + lane], qv3 = qkb[192 + lane];
  float qb = qdotbk[b];
  const float4* Xw = (const float4*)(X + ((size_t)b * Ss + s0) * Dd);

  float m = -INFINITY, l = 0.f;
  float4 a0 = make_float4(0,0,0,0), a1 = a0, a2 = a0, a3 = a0;

  float4 x0 = Xw[lane], x1 = Xw[64 + lane], x2 = Xw[128 + lane], x3 = Xw[192 + lane];
  for (int i = 0; i < tok; i++) {
    size_t nb = (size_t)((i + 1 < tok) ? i + 1 : i) * 256;
    float4 n0 = Xw[nb + lane], n1 = Xw[nb + 64 + lane],
           n2 = Xw[nb + 128 + lane], n3 = Xw[nb + 192 + lane];

    float am = fmaxf(
      fmaxf(fmaxf(fmaxf(fabsf(x0.x), fabsf(x0.y)), fmaxf(fabsf(x0.z), fabsf(x0.w))),
            fmaxf(fmaxf(fabsf(x1.x), fabsf(x1.y)), fmaxf(fabsf(x1.z), fabsf(x1.w)))),
      fmaxf(fmaxf(fmaxf(fabsf(x2.x), fabsf(x2.y)), fmaxf(fabsf(x2.z), fabsf(x2.w))),
            fmaxf(fmaxf(fabsf(x3.x), fabsf(x3.y)), fmaxf(fabsf(x3.z), fabsf(x3.w)))));
    am = wred_max(am);
    float g = am + EPS;
    float c = 127.0f / g;
    float gi = g / 127.0f;

    float q00 = quantf(x0.x, c), q01 = quantf(x0.y, c), q02 = quantf(x0.z, c), q03 = quantf(x0.w, c);
    float q10 = quantf(x1.x, c), q11 = quantf(x1.y, c), q12 = quantf(x1.z, c), q13 = quantf(x1.w, c);
    float q20 = quantf(x2.x, c), q21 = quantf(x2.y, c), q22 = quantf(x2.z, c), q23 = quantf(x2.w, c);
    float q30 = quantf(x3.x, c), q31 = quantf(x3.y, c), q32 = quantf(x3.z, c), q33 = quantf(x3.w, c);

    float dt = q00 * qv0.x + q01 * qv0.y + q02 * qv0.z + q03 * qv0.w
             + q10 * qv1.x + q11 * qv1.y + q12 * qv1.z + q13 * qv1.w
             + q20 * qv2.x + q21 * qv2.y + q22 * qv2.z + q23 * qv2.w
             + q30 * qv3.x + q31 * qv3.y + q32 * qv3.z + q33 * qv3.w;
    dt = wred_sum(dt);

    float score = (dt * gi + qb) * 0.03125f;   // / sqrt(1024)
    float mn  = fmaxf(m, score);
    float scl = expf(m - mn);
    float p   = expf(score - mn);
    l = l * scl + p;
    float cf = p * gi;
    a0.x = a0.x * scl + cf * q00; a0.y = a0.y * scl + cf * q01;
    a0.z = a0.z * scl + cf * q02; a0.w = a0.w * scl + cf * q03;
    a1.x = a1.x * scl + cf * q10; a1.y = a1.y * scl + cf * q11;
    a1.z = a1.z * scl + cf * q12; a1.w = a1.w * scl + cf * q13;
    a2.x = a2.x * scl + cf * q20; a2.y = a2.y * scl + cf * q21;
    a2.z = a2.z * scl + cf * q22; a2.w = a2.w * scl + cf * q23;
    a3.x = a3.x * scl + cf * q30; a3.y = a3.y * scl + cf * q31;
    a3.z = a3.z * scl + cf * q32; a3.w = a3.w * scl + cf * q33;
    m = mn;
    x0 = n0; x1 = n1; x2 = n2; x3 = n3;
  }

  size_t pidx = (size_t)b * NWv + widx;
  float4* tpw = (float4*)t_part + (size_t)pidx * 256;
  tpw[lane] = a0; tpw[64 + lane] = a1; tpw[128 + lane] = a2; tpw[192 + lane] = a3;
  if (lane == 0) { m_part[pidx] = m; l_part[pidx] = l; }
}

// ---------- K7a: per-batch global M and L ----------

__global__ __launch_bounds__(256) void k_ml(
    const float* __restrict__ m_part, const float* __restrict__ l_part,
    float* __restrict__ ML, int NWv)
{
  __shared__ float red[4];
  int b = blockIdx.x, tid = threadIdx.x;
  float mi = -INFINITY;
  for (int i = tid; i < NWv; i += 256) mi = fmaxf(mi, m_part[(size_t)b * NWv + i]);
  float M = blk_reduce(mi, true, red);
  float li = 0.f;
  for (int i = tid; i < NWv; i += 256)
    li += l_part[(size_t)b * NWv + i] * expf(m_part[(size_t)b * NWv + i] - M);
  float L = blk_reduce(li, false, red);
  if (tid == 0) { ML[b * 2] = M; ML[b * 2 + 1] = L; }
}

// ---------- K7b: tree combine stage A (NWv -> 16 per batch) ----------

__global__ __launch_bounds__(256) void k_combA(
    const float* __restrict__ m_part, const float* __restrict__ t_part,
    const float* __restrict__ ML, float* __restrict__ t16, int NWv)
{
  int b = blockIdx.x >> 4, k = blockIdx.x & 15;
  int grp = NWv >> 4;
  int tid = threadIdx.x;
  float M = ML[b * 2];
  float4 acc = make_float4(0,0,0,0);
  for (int i = 0; i < grp; i++) {
    size_t pi = (size_t)b * NWv + k * grp + i;
    float w = expf(m_part[pi] - M);
    float4 tp = ((const float4*)t_part)[pi * 256 + tid];
    acc.x += w * tp.x; acc.y += w * tp.y; acc.z += w * tp.z; acc.w += w * tp.w;
  }
  ((float4*)t16)[((size_t)(b * 16 + k)) * 256 + tid] = acc;
}

// ---------- K7c: tree combine stage B (16 -> 1, normalize) ----------

__global__ __launch_bounds__(256) void k_combB(
    const float* __restrict__ t16, const float* __restrict__ ML,
    float* __restrict__ t)
{
  int b = blockIdx.x, tid = threadIdx.x;
  float invL = 1.0f / ML[b * 2 + 1];
  float4 acc = make_float4(0,0,0,0);
  for (int k = 0; k < 16; k++) {
    float4 v = ((const float4*)t16)[((size_t)(b * 16 + k)) * 256 + tid];
    acc.x += v.x; acc.y += v.y; acc.z += v.z; acc.w += v.w;
  }
  ((float4*)t)[(size_t)b * 256 + tid] =
      make_float4(acc.x * invL, acc.y * invL, acc.z * invL, acc.w * invL);
}

// ---------- K9: quantize combined = [query, ctx] ----------

__global__ __launch_bounds__(256) void k_quant_comb(
    const float* __restrict__ query, const float* __restrict__ ctx,
    char* __restrict__ qout, float* __restrict__ gout)
{
  __shared__ float red[4];
  int b = blockIdx.x, tid = threadIdx.x;
  float4 vq = ((const float4*)(query + (size_t)b * Dd))[tid];
  float4 vc = ((const float4*)(ctx   + (size_t)b * Dd))[tid];
  float am = fmaxf(
      fmaxf(fmaxf(fabsf(vq.x), fabsf(vq.y)), fmaxf(fabsf(vq.z), fabsf(vq.w))),
      fmaxf(fmaxf(fabsf(vc.x), fabsf(vc.y)), fmaxf(fabsf(vc.z), fabsf(vc.w))));
  am = blk_reduce(am, true, red);
  float g = am + EPS;
  float c = 127.0f / g;
  char4 a, d;
  a.x = (signed char)(int)quantf(vq.x, c);
  a.y = (signed char)(int)quantf(vq.y, c);
  a.z = (signed char)(int)quantf(vq.z, c);
  a.w = (signed char)(int)quantf(vq.w, c);
  d.x = (signed char)(int)quantf(vc.x, c);
  d.y = (signed char)(int)quantf(vc.y, c);
  d.z = (signed char)(int)quantf(vc.z, c);
  d.w = (signed char)(int)quantf(vc.w, c);
  ((char4*)qout)[b * 512 + tid] = a;
  ((char4*)qout)[b * 512 + 256 + tid] = d;
  if (tid == 0) gout[b] = g;
}

// ---------- launch ----------

extern "C" void kernel_launch(void* const* d_in, const int* in_sizes, int n_in,
                              void* d_out, int out_size, void* d_ws, size_t ws_size,
                              hipStream_t stream)
{
  const float* query = (const float*)d_in[0];
  const float* X     = (const float*)d_in[1];
  const float* w_q   = (const float*)d_in[2];
  const float* b_q   = (const float*)d_in[3];
  const float* w_k   = (const float*)d_in[4];
  const float* b_k   = (const float*)d_in[5];
  const float* w_v   = (const float*)d_in[6];
  const float* b_v   = (const float*)d_in[7];
  const float* w_c   = (const float*)d_in[8];
  const float* b_c   = (const float*)d_in[9];
  float* out = (float*)d_out;
  char* ws = (char*)d_ws;

  size_t off = 0;
  auto alloc = [&](size_t bytes) -> size_t {
    size_t o = off;
    off += (bytes + 255) & ~(size_t)255;
    return o;
  };
  auto align256 = [](size_t bytes) -> size_t {
    return (bytes + 255) & ~(size_t)255;
  };
  size_t o_part   = alloc(256 * sizeof(double));
  size_t o_scales = alloc(4 * sizeof(float));
  size_t o_gq     = alloc(Bb * sizeof(float));
  size_t o_qq     = alloc((size_t)Bb * Dd);
  size_t o_q      = alloc((size_t)Bb * Dd * 4);
  size_t o_qk     = alloc((size_t)Bb * Dd * 4);
  size_t o_qbk    = alloc(Bb * sizeof(float));
  size_t o_t      = alloc((size_t)Bb * Dd * 4);
  size_t o_ctx    = alloc((size_t)Bb * Dd * 4);
  size_t o_gc     = alloc(Bb * sizeof(float));
  size_t o_qc     = alloc((size_t)Bb * 2 * Dd);
  size_t o_ML     = alloc(Bb * 2 * sizeof(float));
  size_t o_t16    = alloc((size_t)Bb * 16 * Dd * 4);
  size_t base_end = off;

  // qk-partial chunk count, adaptive
  int NCH = 64;
  for (;;) {
    size_t need = base_end
      + align256((size_t)NCH * 8 * Dd * 4)
      + align256((size_t)Bb * 64 * 4) * 2
      + align256((size_t)Bb * 64 * Dd * 4);
    if (need <= ws_size || NCH == 8) break;
    NCH >>= 1;
  }
  int RC = Dd / NCH;
  size_t o_qkp = alloc((size_t)NCH * 8 * Dd * 4);
  size_t qkp_end = off;

  // pass blocks per batch, adaptive; NWv = 4*NW wave-partials per batch
  int NW = 128;
  for (;;) {
    size_t NWv_ = (size_t)NW * 4;
    size_t need = qkp_end
      + align256((size_t)Bb * NWv_ * 4) * 2
      + align256((size_t)Bb * NWv_ * Dd * 4);
    if (need <= ws_size || NW == 16) break;
    NW >>= 1;
  }
  int NWv = NW * 4;
  size_t o_mp = alloc((size_t)Bb * NWv * 4);
  size_t o_lp = alloc((size_t)Bb * NWv * 4);
  size_t o_tp = alloc((size_t)Bb * NWv * Dd * 4);

  double* part   = (double*)(ws + o_part);
  float*  scales = (float*)(ws + o_scales);
  float*  gq     = (float*)(ws + o_gq);
  char*   qq     = (char*)(ws + o_qq);
  float*  qv     = (float*)(ws + o_q);
  float*  qk     = (float*)(ws + o_qk);
  float*  qbk    = (float*)(ws + o_qbk);
  float*  tvec   = (float*)(ws + o_t);
  float*  ctx    = (float*)(ws + o_ctx);
  float*  gc     = (float*)(ws + o_gc);
  char*   qc     = (char*)(ws + o_qc);
  float*  ML     = (float*)(ws + o_ML);
  float*  t16    = (float*)(ws + o_t16);
  float*  qkp    = (float*)(ws + o_qkp);
  float*  mp     = (float*)(ws + o_mp);
  float*  lp     = (float*)(ws + o_lp);
  float*  tp     = (float*)(ws + o_tp);

  k_abs_partial<<<256, 256, 0, stream>>>(w_q, w_k, w_v, w_c, part);
  k_abs_final<<<1, 64, 0, stream>>>(part, scales);
  k_quant_query<<<Bb, 256, 0, stream>>>(query, qq, gq);
  k_tern_gemv_i8<<<(Bb * Dd) / 4, 256, 0, stream>>>(qq, gq, w_q, b_q, scales, 0, qv, Dd, Dd);
  k_qk_part<<<NCH, 256, 0, stream>>>(qv, w_k, scales, qkp, RC);
  k_qk_comb<<<Bb, 256, 0, stream>>>(qkp, qv, b_k, scales, qk, qbk, NCH);
  k_pass<<<Bb * NW, 256, 0, stream>>>(X, qk, qbk, mp, lp, tp, NW);
  k_ml<<<Bb, 256, 0, stream>>>(mp, lp, ML, NWv);
  k_combA<<<Bb * 16, 256, 0, stream>>>(mp, tp, ML, t16, NWv);
  k_combB<<<Bb, 256, 0, stream>>>(t16, ML, tvec);
  k_tern_gemv_f32<<<(Bb * Dd) / 4, 256, 0, stream>>>(tvec, w_v, b_v, scales, 2, ctx, Dd, Dd);
  k_quant_comb<<<Bb, 256, 0, stream>>>(query, ctx, qc, gc);
  k_tern_gemv_i8<<<(Bb * Dd) / 4, 256, 0, stream>>>(qc, gc, w_c, b_c, scales, 3, out, 2 * Dd, Dd);
}

// Round 4
// 135.682 us; speedup vs baseline: 2.8817x; 1.0619x over previous
//
#include <hip/hip_runtime.h>
#include <hip/hip_bf16.h>
#include <math.h>

#define EPS 1e-5f

static constexpr int Bb = 8;
static constexpr int Ss = 8192;
static constexpr int Dd = 1024;   // QD = KD = AD
static constexpr int NW = 64;     // pass blocks per batch
static constexpr int NWv = NW * 4;   // wave partials per batch (256)
static constexpr int TOK = Ss / NWv; // tokens per wave (32)
static constexpr int NCH = 64;    // qk chunk blocks
static constexpr int RC = Dd / NCH;  // rows per chunk (16)

// ---------- helpers ----------

__device__ __forceinline__ float blk_reduce(float v, bool ismax, volatile float* lds) {
#pragma unroll
  for (int msk = 32; msk; msk >>= 1) {
    float o = __shfl_xor(v, msk);
    v = ismax ? fmaxf(v, o) : (v + o);
  }
  int w = threadIdx.x >> 6;
  __syncthreads();
  if ((threadIdx.x & 63) == 0) lds[w] = v;
  __syncthreads();
  return ismax ? fmaxf(fmaxf(lds[0], lds[1]), fmaxf(lds[2], lds[3]))
               : (lds[0] + lds[1] + lds[2] + lds[3]);
}

__device__ __forceinline__ float wred_max(float v) {
#pragma unroll
  for (int msk = 32; msk; msk >>= 1) v = fmaxf(v, __shfl_xor(v, msk));
  return v;
}

__device__ __forceinline__ float wred_sum(float v) {
#pragma unroll
  for (int msk = 32; msk; msk >>= 1) v += __shfl_xor(v, msk);
  return v;
}

__device__ __forceinline__ float quantf(float x, float c) {
  return fminf(fmaxf(rintf(x * c), -128.f), 127.f);
}

__device__ __forceinline__ float ternf(float w, float s) {
  return fminf(fmaxf(rintf(w / s), -1.f), 1.f);
}

// ---------- K1: weight abs-mean scales (fused two-stage, last-arriver) ----------

__global__ __launch_bounds__(256) void k_scales(
    const float* __restrict__ w0, const float* __restrict__ w1,
    const float* __restrict__ w2, const float* __restrict__ w3,
    double* __restrict__ part, float* __restrict__ scales, int* __restrict__ cnt)
{
  int seg = blockIdx.x >> 6;
  int blk = blockIdx.x & 63;
  const float* w = seg == 0 ? w0 : seg == 1 ? w1 : seg == 2 ? w2 : w3;
  int n4 = (seg == 3 ? (1024 * 2048) : (1024 * 1024)) >> 2;
  const float4* w4 = (const float4*)w;
  double acc = 0.0;
  for (int i = blk * 256 + threadIdx.x; i < n4; i += 64 * 256) {
    float4 v = w4[i];
    acc += (double)fabsf(v.x) + (double)fabsf(v.y)
         + (double)fabsf(v.z) + (double)fabsf(v.w);
  }
  __shared__ double sred[256];
  sred[threadIdx.x] = acc;
  __syncthreads();
  for (int s = 128; s > 0; s >>= 1) {
    if (threadIdx.x < s) sred[threadIdx.x] += sred[threadIdx.x + s];
    __syncthreads();
  }
  __shared__ int lastold;
  if (threadIdx.x == 0) {
    part[blockIdx.x] = sred[0];
    __threadfence();
    lastold = atomicAdd(cnt, 1);
  }
  __syncthreads();
  if (lastold == 255) {
    __threadfence();
    if (threadIdx.x < 4) {
      int sg = threadIdx.x;
      double s = 0.0;
      for (int i = 0; i < 64; i++) s += part[sg * 64 + i];
      double n = (sg == 3) ? 2097152.0 : 1048576.0;
      scales[sg] = (float)(s / n) + EPS;
    }
  }
}

// ---------- K2: fused query quant + ternary GEMV (q = bitlinear(query, w_q, b_q)) ----------
// grid: Bb * 256 blocks; block handles batch b, outputs group*4 + wave.

__global__ __launch_bounds__(256) void k_qgemv(
    const float* __restrict__ query, const float* __restrict__ W,
    const float* __restrict__ bias, const float* __restrict__ scales,
    float* __restrict__ out)
{
  __shared__ float cs[Dd];
  __shared__ float red[4];
  int b = blockIdx.x >> 8, grp = blockIdx.x & 255;
  int tid = threadIdx.x, wv = tid >> 6, lane = tid & 63;
  float4 v = ((const float4*)(query + (size_t)b * Dd))[tid];
  float am = fmaxf(fmaxf(fabsf(v.x), fabsf(v.y)), fmaxf(fabsf(v.z), fabsf(v.w)));
  am = blk_reduce(am, true, red);
  float g = am + EPS;
  float c = 127.0f / g;
  float4 qv = make_float4(quantf(v.x, c), quantf(v.y, c), quantf(v.z, c), quantf(v.w, c));
  ((float4*)cs)[tid] = qv;
  __syncthreads();
  float s = scales[0];
  int o = grp * 4 + wv;
  const float4* wr = (const float4*)(W + (size_t)o * Dd);
  float acc = 0.f;
#pragma unroll
  for (int i = 0; i < 4; i++) {
    int idx = i * 64 + lane;
    float4 w4 = wr[idx];
    float4 a4 = ((const float4*)cs)[idx];
    acc += a4.x * ternf(w4.x, s) + a4.y * ternf(w4.y, s)
         + a4.z * ternf(w4.z, s) + a4.w * ternf(w4.w, s);
  }
  acc = wred_sum(acc);
  if (lane == 0) out[(size_t)b * Dd + o] = s * (g / 127.0f) * acc + bias[o];
}

// ---------- K3: qk = s_k * (q @ tern(Wk)) + fused comb via spin barrier ----------
// 64 blocks; phase 1: chunk partials; phase 2 (after all done): d-sliced combine.

__global__ __launch_bounds__(256) void k_qk(
    const float* __restrict__ q, const float* __restrict__ Wk,
    const float* __restrict__ bk, const float* __restrict__ scales,
    float* __restrict__ part, float* __restrict__ qk, float* __restrict__ qdotbk,
    int* __restrict__ cnt)
{
  __shared__ float qs[Bb * RC];
  int ch = blockIdx.x;
  int a0 = ch * RC;
  int tid = threadIdx.x;
  if (tid < Bb * RC) {
    int b = tid / RC, a = tid - b * RC;
    qs[tid] = q[(size_t)b * Dd + a0 + a];
  }
  __syncthreads();
  float s = scales[1];
  float4 acc[Bb];
#pragma unroll
  for (int b = 0; b < Bb; b++) acc[b] = make_float4(0.f, 0.f, 0.f, 0.f);
  const float4* Wr = (const float4*)(Wk + (size_t)a0 * Dd);
  for (int i = 0; i < RC; i++) {
    float4 w = Wr[(size_t)i * 256 + tid];
    float4 t;
    t.x = ternf(w.x, s); t.y = ternf(w.y, s);
    t.z = ternf(w.z, s); t.w = ternf(w.w, s);
#pragma unroll
    for (int b = 0; b < Bb; b++) {
      float qb = qs[b * RC + i];
      acc[b].x += qb * t.x; acc[b].y += qb * t.y;
      acc[b].z += qb * t.z; acc[b].w += qb * t.w;
    }
  }
#pragma unroll
  for (int b = 0; b < Bb; b++)
    ((float4*)part)[((size_t)ch * Bb + b) * 256 + tid] = acc[b];

  // barrier: all 64 blocks co-resident (64 << 256 CUs) -> spin is safe
  __threadfence();
  if (tid == 0) {
    atomicAdd(cnt, 1);
    while (__hip_atomic_load(cnt, __ATOMIC_ACQUIRE, __HIP_MEMORY_SCOPE_AGENT) < NCH) {
      __builtin_amdgcn_s_sleep(8);
    }
  }
  __syncthreads();
  __threadfence();

  // phase 2: block = (b, d-chunk of 128 floats = 32 float4)
  int b = blockIdx.x >> 3, dc = blockIdx.x & 7;
  if (tid < 32) {
    int d4 = dc * 32 + tid;
    float4 a = make_float4(0.f, 0.f, 0.f, 0.f);
    for (int k = 0; k < NCH; k++) {
      float4 p = ((const float4*)part)[((size_t)k * Bb + b) * 256 + d4];
      a.x += p.x; a.y += p.y; a.z += p.z; a.w += p.w;
    }
    ((float4*)qk)[(size_t)b * 256 + d4] = make_float4(s * a.x, s * a.y, s * a.z, s * a.w);
  } else if (dc == 0 && tid >= 64 && tid < 128) {
    int lane = tid - 64;
    float p = 0.f;
    for (int a = lane; a < Dd; a += 64) p += q[(size_t)b * Dd + a] * bk[a];
    p = wred_sum(p);
    if (lane == 0) qdotbk[b] = p;
  }
}

// ---------- K4: fused streaming pass, one WAVE per token, defer-max ----------

__global__ __launch_bounds__(256) void k_pass(
    const float* __restrict__ X, const float* __restrict__ qk,
    const float* __restrict__ qdotbk,
    float* __restrict__ m_part, float* __restrict__ l_part,
    float* __restrict__ t_part)
{
  int b    = blockIdx.x >> 6;
  int wg   = blockIdx.x & 63;
  int wv   = threadIdx.x >> 6;
  int lane = threadIdx.x & 63;
  int widx = wg * 4 + wv;
  int s0   = widx * TOK;

  const float4* qkb = (const float4*)(qk + (size_t)b * Dd);
  float4 qv0 = qkb[lane], qv1 = qkb[64 + lane], qv2 = qkb[128 + lane], qv3 = qkb[192 + lane];
  float qb = qdotbk[b];
  const float4* Xw = (const float4*)(X + ((size_t)b * Ss + s0) * Dd);

  float m = -INFINITY, l = 0.f;
  float4 a0 = make_float4(0,0,0,0), a1 = a0, a2 = a0, a3 = a0;

  float4 x0 = Xw[lane], x1 = Xw[64 + lane], x2 = Xw[128 + lane], x3 = Xw[192 + lane];
  for (int i = 0; i < TOK; i++) {
    size_t nb = (size_t)((i + 1 < TOK) ? i + 1 : i) * 256;
    float4 n0 = Xw[nb + lane], n1 = Xw[nb + 64 + lane],
           n2 = Xw[nb + 128 + lane], n3 = Xw[nb + 192 + lane];

    float am = fmaxf(
      fmaxf(fmaxf(fmaxf(fabsf(x0.x), fabsf(x0.y)), fmaxf(fabsf(x0.z), fabsf(x0.w))),
            fmaxf(fmaxf(fabsf(x1.x), fabsf(x1.y)), fmaxf(fabsf(x1.z), fabsf(x1.w)))),
      fmaxf(fmaxf(fmaxf(fabsf(x2.x), fabsf(x2.y)), fmaxf(fabsf(x2.z), fabsf(x2.w))),
            fmaxf(fmaxf(fabsf(x3.x), fabsf(x3.y)), fmaxf(fabsf(x3.z), fabsf(x3.w)))));
    am = wred_max(am);
    float g = am + EPS;
    float c = 127.0f / g;
    float gi = g / 127.0f;

    float q00 = quantf(x0.x, c), q01 = quantf(x0.y, c), q02 = quantf(x0.z, c), q03 = quantf(x0.w, c);
    float q10 = quantf(x1.x, c), q11 = quantf(x1.y, c), q12 = quantf(x1.z, c), q13 = quantf(x1.w, c);
    float q20 = quantf(x2.x, c), q21 = quantf(x2.y, c), q22 = quantf(x2.z, c), q23 = quantf(x2.w, c);
    float q30 = quantf(x3.x, c), q31 = quantf(x3.y, c), q32 = quantf(x3.z, c), q33 = quantf(x3.w, c);

    float dt = q00 * qv0.x + q01 * qv0.y + q02 * qv0.z + q03 * qv0.w
             + q10 * qv1.x + q11 * qv1.y + q12 * qv1.z + q13 * qv1.w
             + q20 * qv2.x + q21 * qv2.y + q22 * qv2.z + q23 * qv2.w
             + q30 * qv3.x + q31 * qv3.y + q32 * qv3.z + q33 * qv3.w;
    dt = wred_sum(dt);

    float score = (dt * gi + qb) * 0.03125f;   // / sqrt(1024)
    if (score <= m) {                          // wave-uniform: no rescale needed
      float p  = expf(score - m);
      l += p;
      float cf = p * gi;
      a0.x += cf * q00; a0.y += cf * q01; a0.z += cf * q02; a0.w += cf * q03;
      a1.x += cf * q10; a1.y += cf * q11; a1.z += cf * q12; a1.w += cf * q13;
      a2.x += cf * q20; a2.y += cf * q21; a2.z += cf * q22; a2.w += cf * q23;
      a3.x += cf * q30; a3.y += cf * q31; a3.z += cf * q32; a3.w += cf * q33;
    } else {                                   // new max: exp(score-score)=1
      float scl = expf(m - score);
      l = l * scl + 1.0f;
      float cf = gi;
      a0.x = a0.x * scl + cf * q00; a0.y = a0.y * scl + cf * q01;
      a0.z = a0.z * scl + cf * q02; a0.w = a0.w * scl + cf * q03;
      a1.x = a1.x * scl + cf * q10; a1.y = a1.y * scl + cf * q11;
      a1.z = a1.z * scl + cf * q12; a1.w = a1.w * scl + cf * q13;
      a2.x = a2.x * scl + cf * q20; a2.y = a2.y * scl + cf * q21;
      a2.z = a2.z * scl + cf * q22; a2.w = a2.w * scl + cf * q23;
      a3.x = a3.x * scl + cf * q30; a3.y = a3.y * scl + cf * q31;
      a3.z = a3.z * scl + cf * q32; a3.w = a3.w * scl + cf * q33;
      m = score;
    }
    x0 = n0; x1 = n1; x2 = n2; x3 = n3;
  }

  size_t pidx = (size_t)b * NWv + widx;
  float4* tpw = (float4*)t_part + (size_t)pidx * 256;
  tpw[lane] = a0; tpw[64 + lane] = a1; tpw[128 + lane] = a2; tpw[192 + lane] = a3;
  if (threadIdx.x == (unsigned)(wv << 6)) { m_part[pidx] = m; l_part[pidx] = l; }
}

// ---------- K5: fused combine (M,L redundant per block; tree; last-arriver final) ----------
// grid: Bb * 16 blocks; block (b,k) sums partials [k*16, k*16+16); last block per b finalizes.

__global__ __launch_bounds__(256) void k_comb(
    const float* __restrict__ m_part, const float* __restrict__ l_part,
    const float* __restrict__ t_part, float* __restrict__ t16,
    float* __restrict__ t, int* __restrict__ cnt)
{
  __shared__ float red[4];
  int b = blockIdx.x >> 4, k = blockIdx.x & 15;
  int tid = threadIdx.x;
  float mi = m_part[(size_t)b * NWv + tid];
  float M = blk_reduce(mi, true, red);
  float li = l_part[(size_t)b * NWv + tid] * expf(mi - M);
  float L = blk_reduce(li, false, red);

  float4 acc = make_float4(0,0,0,0);
  for (int i = 0; i < 16; i++) {
    size_t pi = (size_t)b * NWv + k * 16 + i;
    float w = expf(m_part[pi] - M);
    float4 tp = ((const float4*)t_part)[pi * 256 + tid];
    acc.x += w * tp.x; acc.y += w * tp.y; acc.z += w * tp.z; acc.w += w * tp.w;
  }
  ((float4*)t16)[((size_t)(b * 16 + k)) * 256 + tid] = acc;

  __shared__ int lastold;
  if (tid == 0) {
    __threadfence();
    lastold = atomicAdd(&cnt[b], 1);
  }
  __syncthreads();
  if (lastold == 15) {
    __threadfence();
    float invL = 1.0f / L;
    float4 a = make_float4(0,0,0,0);
    for (int kk = 0; kk < 16; kk++) {
      float4 v = ((const float4*)t16)[((size_t)(b * 16 + kk)) * 256 + tid];
      a.x += v.x; a.y += v.y; a.z += v.z; a.w += v.w;
    }
    ((float4*)t)[(size_t)b * 256 + tid] =
        make_float4(a.x * invL, a.y * invL, a.z * invL, a.w * invL);
  }
}

// ---------- K6: ternary GEMV, fp32 activations (ctx = bitlinear(t, w_v, b_v)) ----------

__global__ __launch_bounds__(256) void k_tern_gemv_f32(
    const float* __restrict__ act, const float* __restrict__ W,
    const float* __restrict__ bias, const float* __restrict__ scales, int sidx,
    float* __restrict__ out, int K, int N)
{
  int wave = blockIdx.x * 4 + (threadIdx.x >> 6);
  int lane = threadIdx.x & 63;
  int b = wave / N, o = wave - b * N;
  float s = scales[sidx];
  const float4* wr = (const float4*)(W + (size_t)o * K);
  const float4* ar = (const float4*)(act + (size_t)b * K);
  int n4 = K >> 2;
  float acc = 0.f;
  for (int i = lane; i < n4; i += 64) {
    float4 w4 = wr[i];
    float4 a4 = ar[i];
    acc += a4.x * ternf(w4.x, s) + a4.y * ternf(w4.y, s)
         + a4.z * ternf(w4.z, s) + a4.w * ternf(w4.w, s);
  }
  acc = wred_sum(acc);
  if (lane == 0) out[(size_t)b * N + o] = s * acc + bias[o];
}

// ---------- K7: fused [query,ctx] quant + final ternary GEMV ----------
// grid: Bb * 256 blocks; K = 2048.

__global__ __launch_bounds__(256) void k_final(
    const float* __restrict__ query, const float* __restrict__ ctx,
    const float* __restrict__ W, const float* __restrict__ bias,
    const float* __restrict__ scales, float* __restrict__ out)
{
  __shared__ float cs[2 * Dd];
  __shared__ float red[4];
  int b = blockIdx.x >> 8, grp = blockIdx.x & 255;
  int tid = threadIdx.x, wv = tid >> 6, lane = tid & 63;
  float4 vq = ((const float4*)(query + (size_t)b * Dd))[tid];
  float4 vc = ((const float4*)(ctx   + (size_t)b * Dd))[tid];
  float am = fmaxf(
      fmaxf(fmaxf(fabsf(vq.x), fabsf(vq.y)), fmaxf(fabsf(vq.z), fabsf(vq.w))),
      fmaxf(fmaxf(fabsf(vc.x), fabsf(vc.y)), fmaxf(fabsf(vc.z), fabsf(vc.w))));
  am = blk_reduce(am, true, red);
  float g = am + EPS;
  float c = 127.0f / g;
  ((float4*)cs)[tid] = make_float4(quantf(vq.x, c), quantf(vq.y, c), quantf(vq.z, c), quantf(vq.w, c));
  ((float4*)cs)[256 + tid] = make_float4(quantf(vc.x, c), quantf(vc.y, c), quantf(vc.z, c), quantf(vc.w, c));
  __syncthreads();
  float s = scales[3];
  int o = grp * 4 + wv;
  const float4* wr = (const float4*)(W + (size_t)o * 2 * Dd);
  float acc = 0.f;
#pragma unroll
  for (int i = 0; i < 8; i++) {
    int idx = i * 64 + lane;
    float4 w4 = wr[idx];
    float4 a4 = ((const float4*)cs)[idx];
    acc += a4.x * ternf(w4.x, s) + a4.y * ternf(w4.y, s)
         + a4.z * ternf(w4.z, s) + a4.w * ternf(w4.w, s);
  }
  acc = wred_sum(acc);
  if (lane == 0) out[(size_t)b * Dd + o] = s * (g / 127.0f) * acc + bias[o];
}

// ---------- launch ----------

extern "C" void kernel_launch(void* const* d_in, const int* in_sizes, int n_in,
                              void* d_out, int out_size, void* d_ws, size_t ws_size,
                              hipStream_t stream)
{
  const float* query = (const float*)d_in[0];
  const float* X     = (const float*)d_in[1];
  const float* w_q   = (const float*)d_in[2];
  const float* b_q   = (const float*)d_in[3];
  const float* w_k   = (const float*)d_in[4];
  const float* b_k   = (const float*)d_in[5];
  const float* w_v   = (const float*)d_in[6];
  const float* b_v   = (const float*)d_in[7];
  const float* w_c   = (const float*)d_in[8];
  const float* b_c   = (const float*)d_in[9];
  float* out = (float*)d_out;
  char* ws = (char*)d_ws;

  size_t off = 0;
  auto alloc = [&](size_t bytes) -> size_t {
    size_t o = off;
    off += (bytes + 255) & ~(size_t)255;
    return o;
  };
  size_t o_cnt    = alloc(256);                       // [0]=scales, [1]=qk, [2..9]=comb
  size_t o_part   = alloc(256 * sizeof(double));
  size_t o_scales = alloc(4 * sizeof(float));
  size_t o_q      = alloc((size_t)Bb * Dd * 4);
  size_t o_qk     = alloc((size_t)Bb * Dd * 4);
  size_t o_qbk    = alloc(Bb * sizeof(float));
  size_t o_t      = alloc((size_t)Bb * Dd * 4);
  size_t o_ctx    = alloc((size_t)Bb * Dd * 4);
  size_t o_t16    = alloc((size_t)Bb * 16 * Dd * 4);
  size_t o_qkp    = alloc((size_t)NCH * Bb * Dd * 4);
  size_t o_mp     = alloc((size_t)Bb * NWv * 4);
  size_t o_lp     = alloc((size_t)Bb * NWv * 4);
  size_t o_tp     = alloc((size_t)Bb * NWv * Dd * 4);
  (void)ws_size;

  int*    cnt    = (int*)(ws + o_cnt);
  double* part   = (double*)(ws + o_part);
  float*  scales = (float*)(ws + o_scales);
  float*  qv     = (float*)(ws + o_q);
  float*  qk     = (float*)(ws + o_qk);
  float*  qbk    = (float*)(ws + o_qbk);
  float*  tvec   = (float*)(ws + o_t);
  float*  ctx    = (float*)(ws + o_ctx);
  float*  t16    = (float*)(ws + o_t16);
  float*  qkp    = (float*)(ws + o_qkp);
  float*  mp     = (float*)(ws + o_mp);
  float*  lp     = (float*)(ws + o_lp);
  float*  tp     = (float*)(ws + o_tp);

  hipMemsetAsync(ws + o_cnt, 0, 256, stream);
  k_scales<<<256, 256, 0, stream>>>(w_q, w_k, w_v, w_c, part, scales, &cnt[0]);
  k_qgemv<<<Bb * 256, 256, 0, stream>>>(query, w_q, b_q, scales, qv);
  k_qk<<<NCH, 256, 0, stream>>>(qv, w_k, b_k, scales, qkp, qk, qbk, &cnt[1]);
  k_pass<<<Bb * NW, 256, 0, stream>>>(X, qk, qbk, mp, lp, tp);
  k_comb<<<Bb * 16, 256, 0, stream>>>(mp, lp, tp, t16, tvec, &cnt[2]);
  k_tern_gemv_f32<<<(Bb * Dd) / 4, 256, 0, stream>>>(tvec, w_v, b_v, scales, 2, ctx, Dd, Dd);
  k_final<<<Bb * 256, 256, 0, stream>>>(query, ctx, w_c, b_c, scales, out);
}